// Round 14
// baseline (67.325 us; speedup 1.0000x reference)
//
#include <hip/hip_runtime.h>
#include <math.h>

#define HIN 32
#define WIN 32
#define NITER 3

typedef float f2 __attribute__((ext_vector_type(2)));
static __device__ __forceinline__ f2 mk2(float a, float b) { f2 r; r.x = a; r.y = b; return r; }
static __device__ __forceinline__ f2 fma2(f2 a, f2 b, f2 c) { return __builtin_elementwise_fma(a, b, c); }

// ---- 8-lane sum entirely on the VALU pipe (DPP), no ds_swizzle ----
template <int CTRL>
__device__ __forceinline__ float dpp_add(float v) {
    int p = __builtin_amdgcn_update_dpp(0, __float_as_int(v), CTRL, 0xF, 0xF, true);
    return v + __int_as_float(p);
}
__device__ __forceinline__ float sum8(float v) {
    v = dpp_add<0xB1>(v);   // quad_perm xor1
    v = dpp_add<0x4E>(v);   // quad_perm xor2
    v = dpp_add<0x141>(v);  // row_half_mirror
    return v;
}

// ---- stage T taps of flipped weight into pk layout ----
//   wlds[vtap*640 + g*80 + ((m2+g)&3)*20 + l*2 + h]   (v_pk_fma_f32 pairs)
template <int TH, int TW>
__device__ __forceinline__ void stage_weights(const float* __restrict__ weight,
                                              float* __restrict__ wlds, int t) {
    constexpr int T = TH * TW;
    const int sg = (t >> 3) & 7;
    const int sm = t & 7;
    const int l0 = t >> 6;
    const int dbase = sg * 80 + (((sm >> 1) + sg) & 3) * 20 + (sm & 1);
#pragma unroll
    for (int k = 0; k < 2 * T; ++k) {
        const int vtap = k >> 1;
        const int chunk = k & 1;
        const int hh = (TH == 1) ? 1 : ((vtap / TW) * 2);
        const int ww = (TW == 1) ? 1 : ((vtap % TW) * 2);
        const int jflip = (2 - hh) * 3 + (2 - ww);  // compile-time flip
        const int l = chunk * 4 + l0;
        wlds[vtap * 640 + dbase + l * 2] = weight[(chunk * 256 + t) * 9 + jflip];
    }
}

// ---- stage the block's input tile [yi][xi<12][c] (zero-filled OOB) ----
template <int NROWS, int NCHUNK>
__device__ __forceinline__ void stage_input(const float* __restrict__ in,
                                            float* __restrict__ ilds,
                                            int t, int n, int y0, int x0) {
    const int c = t >> 2, r = t & 3;
#pragma unroll
    for (int pp = r; pp < NROWS * NCHUNK; pp += 4) {  // <=4 pairs: 1 iter/thread
        const int yi = pp / NCHUNK, ch = pp % NCHUNK; // compile-time folds
        const int y = y0 + yi;
        const int xc = x0 + ch * 4;
        float4 vv = {0.f, 0.f, 0.f, 0.f};
        if (y < HIN && xc < WIN)
            vv = *(const float4*)(in + (((size_t)(n * 64 + c) * HIN + y) * WIN + xc));
        ilds[(yi * 12 + ch * 4 + 0) * 64 + c] = vv.x;
        ilds[(yi * 12 + ch * 4 + 1) * 64 + c] = vv.y;
        ilds[(yi * 12 + ch * 4 + 2) * 64 + c] = vv.z;
        ilds[(yi * 12 + ch * 4 + 3) * 64 + c] = vv.w;
    }
}

// ---- priors for one position q (m-dim packed f2; invalid taps -> zero votes)
template <int TH, int TW>
__device__ __forceinline__ void compute_pri(const float* __restrict__ ilds,
                                            const float* __restrict__ wlds,
                                            int q, int x0, int pi, int g, int s,
                                            f2 (&pri2)[TH * TW][4]) {
#pragma unroll
    for (int i = 0; i < TH; ++i) {
        const int y = (TH == 1) ? pi : (pi + i);
        const bool vy = (y < HIN);
#pragma unroll
        for (int j = 0; j < TW; ++j) {
            const int v = i * TW + j;
            const int w = (TW == 1) ? 1 : j * 2;
            const int x = (q + w - 1) >> 1;
            if (vy && x < WIN) {  // wave-uniform
                const float4* xp =
                    (const float4*)(ilds + (i * 12 + (x - x0)) * 64 + s * 8);
                float4 x0v = xp[0], x1v = xp[1];
                float xv[8] = {x0v.x, x0v.y, x0v.z, x0v.w, x1v.x, x1v.y, x1v.z, x1v.w};
                const float* wb = wlds + v * 640 + g * 80;
#pragma unroll
                for (int m2 = 0; m2 < 4; ++m2) {
                    const float4* row = (const float4*)(wb + ((m2 + g) & 3) * 20);
                    f2 acc = mk2(0.f, 0.f);
#pragma unroll
                    for (int k = 0; k < 4; ++k) {
                        float4 w4 = row[k];
                        acc = fma2(mk2(xv[2 * k], xv[2 * k]), mk2(w4.x, w4.y), acc);
                        acc = fma2(mk2(xv[2 * k + 1], xv[2 * k + 1]), mk2(w4.z, w4.w), acc);
                    }
                    pri2[v][m2] = acc;
                }
            } else {
#pragma unroll
                for (int m2 = 0; m2 < 4; ++m2) pri2[v][m2] = mk2(0.f, 0.f);
            }
        }
    }
}

// ---- full routing for one position: unnormalized r[] carried across iters
// (normalize is scale-invariant); zero votes add Z = 72-8T to the deferred
// softmax denominator (shift-free: bounded logits). Returns val (+bias).
template <int T>
__device__ __forceinline__ float route_core(const f2 (&pri2)[T][4],
                                            const float* __restrict__ bias,
                                            int g, int s) {
    constexpr float Z = (float)(72 - 8 * T);
    f2 rr[4];
#pragma unroll
    for (int m2 = 0; m2 < 4; ++m2) {
        f2 a = mk2(0.f, 0.f);
#pragma unroll
        for (int v = 0; v < T; ++v) a += pri2[v][m2];
        rr[m2].x = sum8(a.x);
        rr[m2].y = sum8(a.y);
    }
    float r8v = 0.f;
#pragma unroll
    for (int it = 0; it < NITER; ++it) {
        f2 t2 = mk2(0.f, 0.f);
#pragma unroll
        for (int m2 = 0; m2 < 4; ++m2) t2 = fma2(rr[m2], rr[m2], t2);
        const float sn = t2.x + t2.y;
        const float inv = __builtin_amdgcn_rsqf(fmaxf(sn, 1e-24f));
        const f2 inv2 = mk2(inv, inv);
        f2 on2[4];
#pragma unroll
        for (int m2 = 0; m2 < 4; ++m2) on2[m2] = rr[m2] * inv2;

        float a8 = 0.f;
        f2 acc2[4];
#pragma unroll
        for (int m2 = 0; m2 < 4; ++m2) acc2[m2] = mk2(0.f, 0.f);
#pragma unroll
        for (int v = 0; v < T; ++v) {
            f2 d2 = mk2(0.f, 0.f);
#pragma unroll
            for (int m2 = 0; m2 < 4; ++m2) d2 = fma2(pri2[v][m2], on2[m2], d2);
            const float e = __expf(d2.x + d2.y);
            a8 += e;
            const f2 e2 = mk2(e, e);
#pragma unroll
            for (int m2 = 0; m2 < 4; ++m2) acc2[m2] = fma2(e2, pri2[v][m2], acc2[m2]);
        }
#pragma unroll
        for (int m2 = 0; m2 < 4; ++m2) {
            rr[m2].x = sum8(acc2[m2].x);
            rr[m2].y = sum8(acc2[m2].y);
        }
        if (it == NITER - 1) r8v = sum8(a8);  // denominator only needed once
    }
    const float invs = __builtin_amdgcn_rcpf(r8v + Z);  // zero votes: exp(0)=1
    const f2 invs2 = mk2(invs, invs);
    f2 o2[4];
#pragma unroll
    for (int m2 = 0; m2 < 4; ++m2) o2[m2] = rr[m2] * invs2;
    f2 s2 = mk2(0.f, 0.f);
#pragma unroll
    for (int m2 = 0; m2 < 4; ++m2) s2 = fma2(o2[m2], o2[m2], s2);
    const float sn = s2.x + s2.y;
    const float factor =
        sn * __builtin_amdgcn_rcpf(1.f + sn) * __builtin_amdgcn_rsqf(sn + 1e-12f);
    f2 osel = o2[0];
#pragma unroll
    for (int m2 = 1; m2 < 4; ++m2)
        if ((s >> 1) == m2) osel = o2[m2];
    float val = (s & 1) ? osel.y : osel.x;
    return val * factor + bias[g * 8 + s];
}

// ---- dual-position path (T<=2): one wave does q and q+8, sharing every
// weight ds_read between the two positions. Block covers 8 positions.
template <int TH, int TW>
__device__ __forceinline__ void run_dual(
    const float* __restrict__ in, const float* __restrict__ weight,
    const float* __restrict__ bias, float* __restrict__ out,
    float* __restrict__ ilds, float* __restrict__ wlds, float* __restrict__ olds,
    int t, int n, int p, int pi, int qb, int x0) {
    constexpr int T = TH * TW;
    stage_input<TH, (TW == 2 ? 3 : 2)>(in, ilds, t, n, pi, x0);
    stage_weights<TH, TW>(weight, wlds, t);
    __syncthreads();

    const int wave = t >> 6;
    const int lane = t & 63;
    const int g = lane >> 3;
    const int s = lane & 7;
    const int qa = qb + 2 * wave;

    f2 pa[T][4], pb[T][4];
    compute_pri<TH, TW>(ilds, wlds, qa, x0, pi, g, s, pa);
    compute_pri<TH, TW>(ilds, wlds, qa + 8, x0, pi, g, s, pb);

    const float va = route_core<T>(pa, bias, g, s);
    const float vb = route_core<T>(pb, bias, g, s);

    olds[lane * 9 + wave] = va;
    olds[lane * 9 + wave + 4] = vb;
    __syncthreads();
    const int c2 = t >> 2, w = t & 3;
    float* ob = out + (((size_t)n * 64 + c2) * 64 + p) * 64 + qb;
    ob[2 * w] = olds[c2 * 9 + w];
    ob[2 * w + 8] = olds[c2 * 9 + w + 4];
}

// ---- T=4 path: single position/wave (dual would spill: R5 lesson) ----
__device__ __forceinline__ void run_t4(
    const float* __restrict__ in, const float* __restrict__ weight,
    const float* __restrict__ bias, float* __restrict__ out,
    float* __restrict__ ilds, float* __restrict__ wlds, float* __restrict__ olds,
    int t, int n, int p, int pi, int qb, int x0) {
    stage_input<2, 2>(in, ilds, t, n, pi, x0);
    stage_weights<2, 2>(weight, wlds, t);
    __syncthreads();

    const int wave = t >> 6;
    const int lane = t & 63;
    const int g = lane >> 3;
    const int s = lane & 7;

    f2 pa[4][4];
    compute_pri<2, 2>(ilds, wlds, qb + 2 * wave, x0, pi, g, s, pa);
    const float va = route_core<4>(pa, bias, g, s);

    olds[lane * 5 + wave] = va;
    __syncthreads();
    const int c2 = t >> 2, w = t & 3;
    out[(((size_t)n * 64 + c2) * 64 + p) * 64 + qb + 2 * w] = olds[c2 * 5 + w];
}

// Grid 1280, quadrant-interleaved: blockIdx%5 -> {T4,T4,T2v,T2h,T1} so every
// CU gets a balanced mix (T4 blocks do ~3x the LDS work of T1).
__global__ __launch_bounds__(256) void caps_routing(
    const float* __restrict__ in, const float* __restrict__ weight,
    const float* __restrict__ bias, float* __restrict__ out) {
    __shared__ float ilds[2 * 12 * 64];  // input tile [yi][xi][c]
    __shared__ float wlds[4 * 640];      // staged taps (pk layout)
    __shared__ float olds[576];          // output staging
    const int t = threadIdx.x;

    const int b = blockIdx.x;
    const int grp = b / 5;        // 0..255
    const int sel = b - grp * 5;  // 0..4

    if (sel < 2) {  // T4: p odd, q odd; 512 blocks, 4 positions each
        const int idx = grp * 2 + sel;
        const int n = idx >> 8, r = idx & 255;
        const int pi = r >> 3, jq = r & 7;
        run_t4(in, weight, bias, out, ilds, wlds, olds,
               t, n, 2 * pi + 1, pi, 8 * jq + 1, 4 * jq);
    } else {  // dual paths: 256 blocks each, 8 positions each
        const int n = grp >> 7, r = grp & 127;
        const int pi = r >> 2, jq = r & 3;
        if (sel == 2)       // T2v: p odd, q even
            run_dual<2, 1>(in, weight, bias, out, ilds, wlds, olds,
                           t, n, 2 * pi + 1, pi, 16 * jq, 8 * jq);
        else if (sel == 3)  // T2h: p even, q odd
            run_dual<1, 2>(in, weight, bias, out, ilds, wlds, olds,
                           t, n, 2 * pi, pi, 16 * jq + 1, 8 * jq);
        else                // T1: p even, q even
            run_dual<1, 1>(in, weight, bias, out, ilds, wlds, olds,
                           t, n, 2 * pi, pi, 16 * jq, 8 * jq);
    }
}

extern "C" void kernel_launch(void* const* d_in, const int* in_sizes, int n_in,
                              void* d_out, int out_size, void* d_ws, size_t ws_size,
                              hipStream_t stream) {
    const float* in = (const float*)d_in[0];
    const float* weight = (const float*)d_in[1];
    const float* bias = (const float*)d_in[2];
    float* out = (float*)d_out;
    (void)d_ws; (void)ws_size;

    caps_routing<<<1280, 256, 0, stream>>>(in, weight, bias, out);
}